// Round 17
// baseline (1883.468 us; speedup 1.0000x reference)
//
#include <hip/hip_runtime.h>

// SineLSTM: 2-layer LSTM (H=50), B=512 rows, one row per block.
// R19: balanced 2+4-wave layer pipeline, TB=384.
//   R17 (1064us, best): producer(2 waves, pair-lane) + consumer(2 waves,
//   100 dot2/lane) -- tick paced by consumer; 108 arch VGPR < live set ->
//   weights partly AGPR (per-use copy tax inflates VALU issue ~2.4x).
//   R18 (TB=512): regressed -- 2nd block never co-scheduled (occ stuck 23%).
//   R19 marries the proven halves: R17's producer (waves 0-1, pair-lane,
//   50 dot2/lane) + R18's consumer mapping (waves 2-5, quad-lane, ONE row/
//   lane = 50 dot2/lane, 50 wgt half2 + 50 carries ~ 115 regs).
//   launch_bounds(384,3): VGPR cap ~170 -> everything architectural;
//   6 waves/block, 2 blocks/CU = 12 waves/CU = 3 waves/SIMD.
//   Ring buffers / barrier skeleton / deferred out / predict path = R17
//   verbatim. Producers skip the h2 refresh.
// Hazard audit (parity ring, same as R17/R18):
//   h1lds[t&1] W@t(producer) -> R@t+1(refresh all). WAR R@t-1 vs W@t:
//     tick barrier(t) separates. h2lds/h2f32[(t+1)&1] W@t(consumer lead) ->
//     R@t+1(refresh)/R@t+2(deferred)/R@t post-B(predict). WAR ok (ring).
//   Gates cross lanes only via shfl (register-exact).
// Numerics bitwise = R17/R18: DOT25 4-acc order (p->acc(p&3), pairs 0..24),
//   (a0+a2)+(a1+a3), G2 = b2 + wi2-sweep + wh2-sweep in same accs, same
//   activations, same f16 cast points, same output reduce tree.

#define Hh   50
#define TLEN 1024

typedef _Float16 half2v __attribute__((ext_vector_type(2)));

#if __has_builtin(__builtin_amdgcn_fdot2)
#define FDOT2(a, b, c) __builtin_amdgcn_fdot2((a), (b), (c), false)
#else
#define FDOT2(a, b, c) ((c) + (float)(a)[0] * (float)(b)[0] + (float)(a)[1] * (float)(b)[1])
#endif

#define BC(f) __builtin_bit_cast(half2v, f)

// 25-pair dot, proven accumulation order (p -> acc(p&3), pairs 0..24).
#define DOT25(A0, A1, A2, A3, W, H) do {                                     \
    _Pragma("unroll")                                                        \
    for (int pq = 0; pq < 6; ++pq) {                                         \
        A0 = FDOT2(W[4*pq + 0], BC(H[4*pq + 0]), A0);                        \
        A1 = FDOT2(W[4*pq + 1], BC(H[4*pq + 1]), A1);                        \
        A2 = FDOT2(W[4*pq + 2], BC(H[4*pq + 2]), A2);                        \
        A3 = FDOT2(W[4*pq + 3], BC(H[4*pq + 3]), A3);                        \
    }                                                                        \
    A0 = FDOT2(W[24], BC(H[24]), A0);                                        \
} while (0)

__device__ __forceinline__ float fast_sigmoid(float v) {
    return 1.0f / (1.0f + __expf(-v));
}
__device__ __forceinline__ float fast_tanh(float v) {
    return 1.0f - 2.0f / (__expf(2.0f * v) + 1.0f);
}

extern "C" __global__ __launch_bounds__(384, 3)
void sine_lstm_kernel(const float* __restrict__ x,
                      const float* __restrict__ W_ih1,
                      const float* __restrict__ W_hh1,
                      const float* __restrict__ b_ih1,
                      const float* __restrict__ b_hh1,
                      const float* __restrict__ W_ih2,
                      const float* __restrict__ W_hh2,
                      const float* __restrict__ b_ih2,
                      const float* __restrict__ b_hh2,
                      const float* __restrict__ W_lin,
                      const float* __restrict__ b_lin,
                      const int*   __restrict__ predict_p,
                      float* __restrict__ out,
                      int T)
{
    __shared__ __align__(16) float    x_lds[TLEN];
    __shared__ __align__(16) _Float16 h1lds[2][64];   // ring: slot s&1 = h1(s)
    __shared__ __align__(16) _Float16 h2lds[2][64];   // ring: slot s&1 = h2(s)
    __shared__ __align__(16) float    h2f32[2][64];   // fp32 copy for outputs

    const int tid = threadIdx.x;           // 0..383
    const int wv  = tid >> 6;              // 0-1 = L1 producer; 2-5 = L2 consumer
    const int ln  = tid & 63;
    const bool isProd = (wv < 2);
    const int b   = blockIdx.x;
    const int predict = *predict_p;
    const int S = T + predict;

    for (int i = tid; i < TLEN; i += 384)
        x_lds[i] = x[(size_t)b * T + i];
    if (tid < 128) {
        ((_Float16*)h1lds)[tid] = (_Float16)0.0f;
        ((_Float16*)h2lds)[tid] = (_Float16)0.0f;
        ((float*)h2f32)[tid] = 0.0f;
    }

    // ---- producer mapping (R17): pair-lane, 2 rows/lane ----
    //   unit m = (wv&1)*32 + (ln>>1); sub = ln&1
    //   rowP = sub ? 50+m : m (f|i);  rowQ = sub ? 150+m : 100+m (o|g)
    // ---- consumer mapping (R18): quad-lane, 1 row/lane ----
    //   unit cm = (wv-2)*16 + (ln>>2); q = ln&3; row = q*50+cm
    int rowA, rowB;            // the 1-2 gate rows this lane owns
    bool stOwner;              // lane that owns the unit's c/h state
    int  m;                    // unit index owned (for state publish)
    if (isProd) {
        const int pm  = (wv & 1) * 32 + (ln >> 1);
        const int sub = ln & 1;
        const bool mv = (pm < Hh);
        const int mc  = mv ? pm : 0;
        rowA = sub ? (Hh + mc)  : mc;          // f | i
        rowB = sub ? (150 + mc) : (100 + mc);  // o | g
        stOwner = mv && (sub == 0);
        m = mc;
    } else {
        const int cm = ((wv - 2) & 3) * 16 + (ln >> 2);
        const int q  = ln & 3;
        const bool mv = (cm < Hh);
        const int mc  = mv ? cm : 0;
        rowA = q * Hh + mc;                    // own single row
        rowB = rowA;                           // (wB holds W_hh2 of same row)
        stOwner = mv && (q == 0);
        m = mc;
    }

    // weights: producer wA=W_hh1[rowA], wB=W_hh1[rowB] (two rows, one matrix)
    //          consumer wA=W_ih2[rowA], wB=W_hh2[rowA] (one row, two matrices)
    const float* MA = isProd ? W_hh1 : W_ih2;
    const float* MB = isProd ? W_hh1 : W_hh2;
    half2v wA[25], wB[25];
    #pragma unroll
    for (int p = 0; p < 25; ++p) {
        const int k0 = 2 * p, k1 = 2 * p + 1;
        wA[p] = half2v{(_Float16)MA[rowA * Hh + k0], (_Float16)MA[rowA * Hh + k1]};
        wB[p] = half2v{(_Float16)MB[rowB * Hh + k0], (_Float16)MB[rowB * Hh + k1]};
    }
    const float bA = isProd ? (b_ih1[rowA] + b_hh1[rowA]) : (b_ih2[rowA] + b_hh2[rowA]);
    const float bB = b_ih1[rowB] + b_hh1[rowB];     // producer only
    const float wihA = W_ih1[rowA], wihB = W_ih1[rowB];   // producer only
    const float wlin_l = (ln < Hh) ? W_lin[ln] : 0.0f;
    const float blin   = b_lin[0];

    float h1r[25], h2r[25];                // f16-pair carries
    #pragma unroll
    for (int p = 0; p < 25; ++p) { h1r[p] = 0.0f; h2r[p] = 0.0f; }
    float cst = 0.0f;   // c1 on producer owner lanes, c2 on consumer lead lanes

    __syncthreads();    // init complete

    for (int t = 0; t <= S; ++t) {
        __syncthreads();                   // tick barrier
        // ---- refresh carries: h1(t-1) all waves; h2(t-2) consumers only ----
        {
            const int s1 = (t + 1) & 1;    // == (t-1)&1
            #pragma unroll
            for (int L = 0; L < 6; ++L) {
                float4 f = *(const float4*)&h1lds[s1][8 * L];
                h1r[4*L] = f.x; h1r[4*L+1] = f.y; h1r[4*L+2] = f.z; h1r[4*L+3] = f.w;
            }
            h1r[24] = *(const float*)&h1lds[s1][48];
        }
        if (!isProd) {
            const int s2 = t & 1;          // == (t-2)&1
            #pragma unroll
            for (int L = 0; L < 6; ++L) {
                float4 f = *(const float4*)&h2lds[s2][8 * L];
                h2r[4*L] = f.x; h2r[4*L+1] = f.y; h2r[4*L+2] = f.z; h2r[4*L+3] = f.w;
            }
            h2r[24] = *(const float*)&h2lds[s2][48];
        }
        const bool pred = (t >= T);

        // ---- consumer: G2+U2 for step t-1 (t>=1); quad exchange ----
        if (!isProd && t >= 1) {
            float a0 = bA, a1 = 0.0f, a2 = 0.0f, a3 = 0.0f;
            DOT25(a0, a1, a2, a3, wA, h1r);     // wi2 sweep
            DOT25(a0, a1, a2, a3, wB, h2r);     // wh2 sweep
            float g  = (a0 + a2) + (a1 + a3);
            float v1 = __shfl_xor(g, 1);        // lead gets f
            float v2 = __shfl_xor(g, 2);        // lead gets g-gate
            float v3 = __shfl_xor(g, 3);        // lead gets o
            if (stOwner) {
                float cn = fast_sigmoid(v1) * cst + fast_sigmoid(g) * fast_tanh(v2);
                cst = cn;
                float hn = fast_sigmoid(v3) * fast_tanh(cn);
                h2lds[(t + 1) & 1][m] = (_Float16)hn;   // slot (t-1)&1
                h2f32[(t + 1) & 1][m] = hn;
            }
        }

        // ---- wave0: deferred out(t-2) from h2f32 ring ----
        if (wv == 0 && t >= 2 && t <= T) {
            float part = (ln < Hh) ? h2f32[t & 1][ln] * wlin_l : 0.0f;
            #pragma unroll
            for (int off = 32; off > 0; off >>= 1)
                part += __shfl_down(part, off);
            if (ln == 0) out[(size_t)b * S + (t - 2)] = part + blin;
        }

        if (!pred) {
            // ---- teacher: producer G1+U1 for step t; pair exchange ----
            if (isProd) {
                float xin = x_lds[t];
                float p0 = bA + xin * wihA, p1 = 0.0f, p2 = 0.0f, p3 = 0.0f;
                float q0 = bB + xin * wihB, q1 = 0.0f, q2 = 0.0f, q3 = 0.0f;
                DOT25(p0, p1, p2, p3, wA, h1r);
                DOT25(q0, q1, q2, q3, wB, h1r);
                float gP = (p0 + p2) + (p1 + p3);
                float gQ = (q0 + q2) + (q1 + q3);
                float eP = __shfl_xor(gP, 1);   // even lane gets f; odd gets i
                float eQ = __shfl_xor(gQ, 1);   // even lane gets o; odd gets g
                if (stOwner) {                  // even lane: i=gP f=eP g=gQ o=eQ
                    float cn = fast_sigmoid(eP) * cst + fast_sigmoid(gP) * fast_tanh(gQ);
                    cst = cn;
                    h1lds[t & 1][m] = (_Float16)(fast_sigmoid(eQ) * fast_tanh(cn));
                }
            }
        } else {
            // ---- predict tick: consumer published h2(t-1); sync, make o ----
            __syncthreads();               // barrier B
            float part = (ln < Hh) ? h2f32[(t + 1) & 1][ln] * wlin_l : 0.0f;
            #pragma unroll
            for (int off = 32; off > 0; off >>= 1)
                part += __shfl_down(part, off);
            float o = __shfl(part, 0) + blin;
            if (tid == 0) out[(size_t)b * S + (t - 1)] = o;
            if (isProd && t < S) {         // producer G1(t) with xin = o(t-1)
                float p0 = bA + o * wihA, p1 = 0.0f, p2 = 0.0f, p3 = 0.0f;
                float q0 = bB + o * wihB, q1 = 0.0f, q2 = 0.0f, q3 = 0.0f;
                DOT25(p0, p1, p2, p3, wA, h1r);
                DOT25(q0, q1, q2, q3, wB, h1r);
                float gP = (p0 + p2) + (p1 + p3);
                float gQ = (q0 + q2) + (q1 + q3);
                float eP = __shfl_xor(gP, 1);
                float eQ = __shfl_xor(gQ, 1);
                if (stOwner) {
                    float cn = fast_sigmoid(eP) * cst + fast_sigmoid(gP) * fast_tanh(gQ);
                    cst = cn;
                    h1lds[t & 1][m] = (_Float16)(fast_sigmoid(eQ) * fast_tanh(cn));
                }
            }
        }
    }
}

extern "C" void kernel_launch(void* const* d_in, const int* in_sizes, int n_in,
                              void* d_out, int out_size, void* d_ws, size_t ws_size,
                              hipStream_t stream) {
    const float* x      = (const float*)d_in[0];
    const float* W_ih1  = (const float*)d_in[1];
    const float* W_hh1  = (const float*)d_in[2];
    const float* b_ih1  = (const float*)d_in[3];
    const float* b_hh1  = (const float*)d_in[4];
    const float* W_ih2  = (const float*)d_in[5];
    const float* W_hh2  = (const float*)d_in[6];
    const float* b_ih2  = (const float*)d_in[7];
    const float* b_hh2  = (const float*)d_in[8];
    const float* W_lin  = (const float*)d_in[9];
    const float* b_lin  = (const float*)d_in[10];
    const int*   pred   = (const int*)d_in[11];
    float* out = (float*)d_out;

    const int B = 512;                 // fixed by setup_inputs
    const int T = in_sizes[0] / B;     // 1024

    dim3 grid(B), block(384);
    hipLaunchKernelGGL(sine_lstm_kernel, grid, block, 0, stream,
                       x, W_ih1, W_hh1, b_ih1, b_hh1,
                       W_ih2, W_hh2, b_ih2, b_hh2,
                       W_lin, b_lin, pred, out, T);
}

// Round 18
// 1570.762 us; speedup vs baseline: 1.1991x; 1.1991x over previous
//
#include <hip/hip_runtime.h>

// SineLSTM: 2-layer LSTM (H=50), B=512 rows, one row per block.
// R20: SYMMETRIC layer pipeline. R17 (1064us, best) paced by its consumer
// waves (100 dot2/lane) while producers (50) idle at the barrier; R18/R19
// proved TB>256 never co-schedules 2 blocks/CU (occupancy 18-24%), so the
// fix must stay TB=256. Key fact: with pipeline skew, G2(t-1) and G1(t)
// are mutually independent (both need only ring state from barrier(t)).
// So EVERY lane does its row's slice of BOTH layers: quad mapping (lane
// 4m+q owns gate row q*50+m, R18-proven) -> 50 dot2 (G2) + 25 dot2 (G1) =
// 75 dot2/lane, uniform across all 4 waves; no straggler. U1+U2 both on
// the quad-lead lane (owns c1,c2,h1,h2 of unit m -- lane-local). Gate
// exchange = 3+3 __shfl_xor. One barrier per teacher tick; ring buffers,
// deferred out(t-2) on wave0, predict ticks add barrier B -- R17 verbatim.
// ~150 VGPR (75 wgt half2 + 50 carries) < 256 cap @ launch_bounds(256,2).
// Hazard audit (parity ring, barrier(t) separates all R(t-1)/W(t) pairs):
//   h1lds[t&1]   W@t (U1, pre-next-barrier) -> R@t+1 refresh. WAR: prior
//                R of slot t&1 was refresh@t-1; barrier(t) separates.
//   h2lds/h2f32[(t+1)&1] W@t (U2) -> R@t+1 refresh / R@t+2 deferred /
//                R@t post-B (predict). WAR symmetric.
//   In-tick: refresh reads slots (t+1)&1 (h1) / t&1 (h2); U1 writes t&1
//   (h1) / U2 writes (t+1)&1 (h2) -- different arrays, no overlap.
// Numerics bitwise = R17/R18: DOT25 4-acc order (p->acc(p&3), pairs 0..24),
// (a0+a2)+(a1+a3), G2 = b2 + wi2-sweep + wh2-sweep, same activations, same
// f16 cast points, same output reduce tree.

#define Hh   50
#define TLEN 1024

typedef _Float16 half2v __attribute__((ext_vector_type(2)));

#if __has_builtin(__builtin_amdgcn_fdot2)
#define FDOT2(a, b, c) __builtin_amdgcn_fdot2((a), (b), (c), false)
#else
#define FDOT2(a, b, c) ((c) + (float)(a)[0] * (float)(b)[0] + (float)(a)[1] * (float)(b)[1])
#endif

#define BC(f) __builtin_bit_cast(half2v, f)

// 25-pair dot, proven accumulation order (p -> acc(p&3), pairs 0..24).
#define DOT25(A0, A1, A2, A3, W, H) do {                                     \
    _Pragma("unroll")                                                        \
    for (int pq = 0; pq < 6; ++pq) {                                         \
        A0 = FDOT2(W[4*pq + 0], BC(H[4*pq + 0]), A0);                        \
        A1 = FDOT2(W[4*pq + 1], BC(H[4*pq + 1]), A1);                        \
        A2 = FDOT2(W[4*pq + 2], BC(H[4*pq + 2]), A2);                        \
        A3 = FDOT2(W[4*pq + 3], BC(H[4*pq + 3]), A3);                        \
    }                                                                        \
    A0 = FDOT2(W[24], BC(H[24]), A0);                                        \
} while (0)

__device__ __forceinline__ float fast_sigmoid(float v) {
    return 1.0f / (1.0f + __expf(-v));
}
__device__ __forceinline__ float fast_tanh(float v) {
    return 1.0f - 2.0f / (__expf(2.0f * v) + 1.0f);
}

extern "C" __global__ __launch_bounds__(256, 2)
void sine_lstm_kernel(const float* __restrict__ x,
                      const float* __restrict__ W_ih1,
                      const float* __restrict__ W_hh1,
                      const float* __restrict__ b_ih1,
                      const float* __restrict__ b_hh1,
                      const float* __restrict__ W_ih2,
                      const float* __restrict__ W_hh2,
                      const float* __restrict__ b_ih2,
                      const float* __restrict__ b_hh2,
                      const float* __restrict__ W_lin,
                      const float* __restrict__ b_lin,
                      const int*   __restrict__ predict_p,
                      float* __restrict__ out,
                      int T)
{
    __shared__ __align__(16) float    x_lds[TLEN];
    __shared__ __align__(16) _Float16 h1lds[2][64];   // ring: slot s&1 = h1(s)
    __shared__ __align__(16) _Float16 h2lds[2][64];   // ring: slot s&1 = h2(s)
    __shared__ __align__(16) float    h2f32[2][64];   // fp32 copy for outputs

    const int tid = threadIdx.x;           // 0..255
    const int wv  = tid >> 6;              // wave 0..3
    const int ln  = tid & 63;
    const int b   = blockIdx.x;
    const int predict = *predict_p;
    const int S = T + predict;

    for (int i = tid; i < TLEN; i += 256)
        x_lds[i] = x[(size_t)b * T + i];
    if (tid < 128) {
        ((_Float16*)h1lds)[tid] = (_Float16)0.0f;
        ((_Float16*)h2lds)[tid] = (_Float16)0.0f;
        ((float*)h2f32)[tid] = 0.0f;
    }

    // quad mapping (R18-proven): unit m = wv*16 + (ln>>2), gate q = ln&3;
    // this lane owns gate row q*50+m for BOTH layers.
    const int  m    = (wv << 4) + (ln >> 2);     // 0..63
    const int  q    = ln & 3;
    const bool mval = (m < Hh);
    const bool lead = mval && (q == 0);          // owns unit m's c1,c2,h1,h2
    const int  rc   = mval ? (q * Hh + m) : 0;   // own gate row (clamped)

    half2v wG1[25], wI2[25], wH2[25];
    #pragma unroll
    for (int p = 0; p < 25; ++p) {
        const int k0 = 2 * p, k1 = 2 * p + 1;
        wG1[p] = half2v{(_Float16)W_hh1[rc * Hh + k0], (_Float16)W_hh1[rc * Hh + k1]};
        wI2[p] = half2v{(_Float16)W_ih2[rc * Hh + k0], (_Float16)W_ih2[rc * Hh + k1]};
        wH2[p] = half2v{(_Float16)W_hh2[rc * Hh + k0], (_Float16)W_hh2[rc * Hh + k1]};
    }
    const float b1R  = b_ih1[rc] + b_hh1[rc];
    const float b2R  = b_ih2[rc] + b_hh2[rc];
    const float wihR = W_ih1[rc];
    const float wlin_l = (ln < Hh) ? W_lin[ln] : 0.0f;
    const float blin   = b_lin[0];

    float h1r[25], h2r[25];                // f16-pair carries
    #pragma unroll
    for (int p = 0; p < 25; ++p) { h1r[p] = 0.0f; h2r[p] = 0.0f; }
    float c1 = 0.0f, c2 = 0.0f;            // lead-lane cell states

    __syncthreads();    // init complete

    for (int t = 0; t <= S; ++t) {
        __syncthreads();                   // tick barrier
        // ---- refresh carries: h1(t-1) and h2(t-2) (all waves) ----
        {
            const int s1 = (t + 1) & 1;    // == (t-1)&1
            #pragma unroll
            for (int L = 0; L < 6; ++L) {
                float4 f = *(const float4*)&h1lds[s1][8 * L];
                h1r[4*L] = f.x; h1r[4*L+1] = f.y; h1r[4*L+2] = f.z; h1r[4*L+3] = f.w;
            }
            h1r[24] = *(const float*)&h1lds[s1][48];
            const int s2 = t & 1;          // == (t-2)&1
            #pragma unroll
            for (int L = 0; L < 6; ++L) {
                float4 f = *(const float4*)&h2lds[s2][8 * L];
                h2r[4*L] = f.x; h2r[4*L+1] = f.y; h2r[4*L+2] = f.z; h2r[4*L+3] = f.w;
            }
            h2r[24] = *(const float*)&h2lds[s2][48];
        }
        const bool pred = (t >= T);

        // ---- L2 slice: G2(t-1) + U2 (t>=1); quad exchange ----
        if (t >= 1) {
            float a0 = b2R, a1 = 0.0f, a2 = 0.0f, a3 = 0.0f;
            DOT25(a0, a1, a2, a3, wI2, h1r);    // wi2 sweep
            DOT25(a0, a1, a2, a3, wH2, h2r);    // wh2 sweep
            float g  = (a0 + a2) + (a1 + a3);
            float v1 = __shfl_xor(g, 1);        // lead gets f
            float v2 = __shfl_xor(g, 2);        // lead gets g-gate
            float v3 = __shfl_xor(g, 3);        // lead gets o
            if (lead) {
                float cn = fast_sigmoid(v1) * c2 + fast_sigmoid(g) * fast_tanh(v2);
                c2 = cn;
                float hn = fast_sigmoid(v3) * fast_tanh(cn);
                h2lds[(t + 1) & 1][m] = (_Float16)hn;   // slot (t-1)&1
                h2f32[(t + 1) & 1][m] = hn;
            }
        }

        // ---- wave0: deferred out(t-2) from h2f32 ring ----
        if (wv == 0 && t >= 2 && t <= T) {
            float part = (ln < Hh) ? h2f32[t & 1][ln] * wlin_l : 0.0f;
            #pragma unroll
            for (int off = 32; off > 0; off >>= 1)
                part += __shfl_down(part, off);
            if (ln == 0) out[(size_t)b * S + (t - 2)] = part + blin;
        }

        if (!pred) {
            // ---- L1 slice: G1(t) + U1 (teacher) ----
            float xin = x_lds[t];
            float a0 = b1R + xin * wihR, a1 = 0.0f, a2 = 0.0f, a3 = 0.0f;
            DOT25(a0, a1, a2, a3, wG1, h1r);
            float g  = (a0 + a2) + (a1 + a3);
            float v1 = __shfl_xor(g, 1);
            float v2 = __shfl_xor(g, 2);
            float v3 = __shfl_xor(g, 3);
            if (lead) {
                float cn = fast_sigmoid(v1) * c1 + fast_sigmoid(g) * fast_tanh(v2);
                c1 = cn;
                h1lds[t & 1][m] = (_Float16)(fast_sigmoid(v3) * fast_tanh(cn));
            }
        } else {
            // ---- predict tick: U2 published h2(t-1); sync, make o, G1(t) ----
            __syncthreads();               // barrier B
            float part = (ln < Hh) ? h2f32[(t + 1) & 1][ln] * wlin_l : 0.0f;
            #pragma unroll
            for (int off = 32; off > 0; off >>= 1)
                part += __shfl_down(part, off);
            float o = __shfl(part, 0) + blin;
            if (tid == 0) out[(size_t)b * S + (t - 1)] = o;
            if (t < S) {                   // G1(t) with xin = o(t-1)
                float a0 = b1R + o * wihR, a1 = 0.0f, a2 = 0.0f, a3 = 0.0f;
                DOT25(a0, a1, a2, a3, wG1, h1r);
                float g  = (a0 + a2) + (a1 + a3);
                float v1 = __shfl_xor(g, 1);
                float v2 = __shfl_xor(g, 2);
                float v3 = __shfl_xor(g, 3);
                if (lead) {
                    float cn = fast_sigmoid(v1) * c1 + fast_sigmoid(g) * fast_tanh(v2);
                    c1 = cn;
                    h1lds[t & 1][m] = (_Float16)(fast_sigmoid(v3) * fast_tanh(cn));
                }
            }
        }
    }
}

extern "C" void kernel_launch(void* const* d_in, const int* in_sizes, int n_in,
                              void* d_out, int out_size, void* d_ws, size_t ws_size,
                              hipStream_t stream) {
    const float* x      = (const float*)d_in[0];
    const float* W_ih1  = (const float*)d_in[1];
    const float* W_hh1  = (const float*)d_in[2];
    const float* b_ih1  = (const float*)d_in[3];
    const float* b_hh1  = (const float*)d_in[4];
    const float* W_ih2  = (const float*)d_in[5];
    const float* W_hh2  = (const float*)d_in[6];
    const float* b_ih2  = (const float*)d_in[7];
    const float* b_hh2  = (const float*)d_in[8];
    const float* W_lin  = (const float*)d_in[9];
    const float* b_lin  = (const float*)d_in[10];
    const int*   pred   = (const int*)d_in[11];
    float* out = (float*)d_out;

    const int B = 512;                 // fixed by setup_inputs
    const int T = in_sizes[0] / B;     // 1024

    dim3 grid(B), block(256);
    hipLaunchKernelGGL(sine_lstm_kernel, grid, block, 0, stream,
                       x, W_ih1, W_hh1, b_ih1, b_hh1,
                       W_ih2, W_hh2, b_ih2, b_hh2,
                       W_lin, b_lin, pred, out, T);
}

// Round 20
// 930.624 us; speedup vs baseline: 2.0239x; 1.6879x over previous
//
#include <hip/hip_runtime.h>

// SineLSTM: 2-layer LSTM (H=50), B=512 rows, one row per block.
// R22: single-wave-per-layer pipeline. R21's shadow race taught the rule:
// a wave may only re-read h it wrote ENTIRELY itself. So: wave0 owns ALL of
// layer 1 (lane l = unit l, all 4 gate rows l,50+l,100+l,150+l: U1 fully
// in-lane, wave writes all 50 h1); wave1 owns ALL of layer 2 likewise.
// R17's pipeline skew (G1(t) ∥ G2(t-1), one-way h1->G2 dependency) gives
// ONE barrier per teacher tick; every LDS store->read pair crosses it.
// No gate exchange anywhere (4 gates in-lane); no shuffles except output.
// Registers: wave1 = 200 weight half2 + 16 acc + chunk temps ~ 230 < 256
// cap (R14's spill came from 300+; launch_bounds(128,1)). h read inline
// per float4 chunk -- no persistent carry arrays.
// Hazard audit (parity ring, slot s&1 = h(s)):
//   h1lds[t&1]: W wave0@t -> R wave0 G1@t+1 + wave1 G2@t+1 (both post-
//     barrier(t+1)). WAR: prior R of slot @t-1 pre-barrier(t). OK.
//   h2lds/h2f32[(t+1)&1]: W wave1@t -> R wave1 wh2@t+1 / wave0 deferred@t+2
//     (h2f32[t&1] read@t crosses barrier) / post-B reduce@t (predict). OK.
// Numerics bitwise = R10..R21 lineage: per-row p->acc(p&3) ascending
// (chunks L=0..5 of 4 + tail p=24 into acc0), (a0+a2)+(a1+a3), G2 = b2 +
// wi2-sweep then wh2-sweep, same activations, same f16 cast points, same
// output reduce tree.

#define Hh   50
#define TLEN 1024

typedef _Float16 half2v __attribute__((ext_vector_type(2)));

#if __has_builtin(__builtin_amdgcn_fdot2)
#define FDOT2(a, b, c) __builtin_amdgcn_fdot2((a), (b), (c), false)
#else
#define FDOT2(a, b, c) ((c) + (float)(a)[0] * (float)(b)[0] + (float)(a)[1] * (float)(b)[1])
#endif

#define BC(f) __builtin_bit_cast(half2v, f)

__device__ __forceinline__ float fast_sigmoid(float v) {
    return 1.0f / (1.0f + __expf(-v));
}
__device__ __forceinline__ float fast_tanh(float v) {
    return 1.0f - 2.0f / (__expf(2.0f * v) + 1.0f);
}

extern "C" __global__ __launch_bounds__(128, 1)
void sine_lstm_kernel(const float* __restrict__ x,
                      const float* __restrict__ W_ih1,
                      const float* __restrict__ W_hh1,
                      const float* __restrict__ b_ih1,
                      const float* __restrict__ b_hh1,
                      const float* __restrict__ W_ih2,
                      const float* __restrict__ W_hh2,
                      const float* __restrict__ b_ih2,
                      const float* __restrict__ b_hh2,
                      const float* __restrict__ W_lin,
                      const float* __restrict__ b_lin,
                      const int*   __restrict__ predict_p,
                      float* __restrict__ out,
                      int T)
{
    __shared__ __align__(16) float    x_lds[TLEN];
    __shared__ __align__(16) _Float16 h1lds[2][64];   // ring: slot s&1 = h1(s)
    __shared__ __align__(16) _Float16 h2lds[2][64];   // ring: slot s&1 = h2(s)
    __shared__ __align__(16) float    h2f32[2][64];   // fp32 copy for outputs

    const int tid = threadIdx.x;           // 0..127
    const int wv  = tid >> 6;              // 0 = layer1 wave, 1 = layer2 wave
    const int ln  = tid & 63;
    const bool isProd = (wv == 0);
    const int b   = blockIdx.x;
    const int predict = *predict_p;
    const int S = T + predict;

    for (int i = tid; i < TLEN; i += 128)
        x_lds[i] = x[(size_t)b * T + i];
    // zero both parities of all state buffers (128 threads cover 2*64 each)
    ((_Float16*)h1lds)[tid] = (_Float16)0.0f;
    ((_Float16*)h2lds)[tid] = (_Float16)0.0f;
    ((float*)h2f32)[tid] = 0.0f;

    const bool act = (ln < Hh);            // lane ln = unit ln (this layer)

    // all 4 gate rows of unit ln for THIS wave's layer, f16 pairs (25)
    // producer: wgtA = W_hh1 rows (wgtB unused-but-allocated);
    // consumer: wgtA = W_ih2 rows, wgtB = W_hh2 rows.
    const float* MA = isProd ? W_hh1 : W_ih2;
    const float* MB = isProd ? W_hh1 : W_hh2;
    half2v wgtA[4][25], wgtB[4][25];
    float  bv[4], wih[4];
    #pragma unroll
    for (int q = 0; q < 4; ++q) {
        const int r = act ? (q * Hh + ln) : 0;
        bv[q]  = isProd ? (b_ih1[r] + b_hh1[r]) : (b_ih2[r] + b_hh2[r]);
        wih[q] = W_ih1[r];                 // producer only
        #pragma unroll
        for (int p = 0; p < 25; ++p) {
            wgtA[q][p] = half2v{(_Float16)MA[r * Hh + 2*p], (_Float16)MA[r * Hh + 2*p + 1]};
            wgtB[q][p] = half2v{(_Float16)MB[r * Hh + 2*p], (_Float16)MB[r * Hh + 2*p + 1]};
        }
    }
    const float wlin_l = act ? W_lin[ln] : 0.0f;
    const float blin   = b_lin[0];
    float cst = 0.0f;                      // c1 (wave0) / c2 (wave1), in-lane

    __syncthreads();                       // init complete

    for (int t = 0; t <= S; ++t) {
        __syncthreads();                   // tick barrier (full fence)
        const bool pred = (t >= T);

        // ======== wave1: G2(t-1) + U2, fully in-lane (t>=1) ========
        if (!isProd && t >= 1) {
            float acc[4][4];
            #pragma unroll
            for (int q = 0; q < 4; ++q) {
                acc[q][0] = bv[q]; acc[q][1] = 0.0f; acc[q][2] = 0.0f; acc[q][3] = 0.0f;
            }
            const int s1 = (t + 1) & 1;    // h1(t-1)
            #pragma unroll
            for (int L = 0; L < 6; ++L) {  // wi2 sweep, p = 4L+j ascending
                float4 f = *(const float4*)&h1lds[s1][8 * L];
                #pragma unroll
                for (int j = 0; j < 4; ++j) {
                    const float hj = (&f.x)[j];
                    #pragma unroll
                    for (int q = 0; q < 4; ++q)
                        acc[q][j] = FDOT2(wgtA[q][4*L + j], BC(hj), acc[q][j]);
                }
            }
            {
                const float h24 = *(const float*)&h1lds[s1][48];
                #pragma unroll
                for (int q = 0; q < 4; ++q)
                    acc[q][0] = FDOT2(wgtA[q][24], BC(h24), acc[q][0]);
            }
            const int s2 = t & 1;          // h2(t-2)
            #pragma unroll
            for (int L = 0; L < 6; ++L) {  // wh2 sweep
                float4 f = *(const float4*)&h2lds[s2][8 * L];
                #pragma unroll
                for (int j = 0; j < 4; ++j) {
                    const float hj = (&f.x)[j];
                    #pragma unroll
                    for (int q = 0; q < 4; ++q)
                        acc[q][j] = FDOT2(wgtB[q][4*L + j], BC(hj), acc[q][j]);
                }
            }
            {
                const float h24 = *(const float*)&h2lds[s2][48];
                #pragma unroll
                for (int q = 0; q < 4; ++q)
                    acc[q][0] = FDOT2(wgtB[q][24], BC(h24), acc[q][0]);
            }
            float gi = (acc[0][0] + acc[0][2]) + (acc[0][1] + acc[0][3]);
            float gf = (acc[1][0] + acc[1][2]) + (acc[1][1] + acc[1][3]);
            float gg = (acc[2][0] + acc[2][2]) + (acc[2][1] + acc[2][3]);
            float go = (acc[3][0] + acc[3][2]) + (acc[3][1] + acc[3][3]);
            if (act) {
                float cn = fast_sigmoid(gf) * cst + fast_sigmoid(gi) * fast_tanh(gg);
                cst = cn;
                float hn = fast_sigmoid(go) * fast_tanh(cn);
                h2lds[(t + 1) & 1][ln] = (_Float16)hn;   // slot (t-1)&1
                h2f32[(t + 1) & 1][ln] = hn;
            }
        }

        // ======== wave0: deferred out(t-2) from h2f32 ring ========
        if (isProd && t >= 2 && t <= T) {
            float part = act ? h2f32[t & 1][ln] * wlin_l : 0.0f;
            #pragma unroll
            for (int off = 32; off > 0; off >>= 1)
                part += __shfl_down(part, off);
            if (ln == 0) out[(size_t)b * S + (t - 2)] = part + blin;
        }

        if (!pred) {
            // ======== wave0: G1(t) + U1, fully in-lane (teacher) ========
            if (isProd) {
                const float xin = x_lds[t];
                float acc[4][4];
                #pragma unroll
                for (int q = 0; q < 4; ++q) {
                    acc[q][0] = bv[q] + xin * wih[q];
                    acc[q][1] = 0.0f; acc[q][2] = 0.0f; acc[q][3] = 0.0f;
                }
                const int s1 = (t + 1) & 1;    // h1(t-1)
                #pragma unroll
                for (int L = 0; L < 6; ++L) {
                    float4 f = *(const float4*)&h1lds[s1][8 * L];
                    #pragma unroll
                    for (int j = 0; j < 4; ++j) {
                        const float hj = (&f.x)[j];
                        #pragma unroll
                        for (int q = 0; q < 4; ++q)
                            acc[q][j] = FDOT2(wgtA[q][4*L + j], BC(hj), acc[q][j]);
                    }
                }
                {
                    const float h24 = *(const float*)&h1lds[s1][48];
                    #pragma unroll
                    for (int q = 0; q < 4; ++q)
                        acc[q][0] = FDOT2(wgtA[q][24], BC(h24), acc[q][0]);
                }
                float gi = (acc[0][0] + acc[0][2]) + (acc[0][1] + acc[0][3]);
                float gf = (acc[1][0] + acc[1][2]) + (acc[1][1] + acc[1][3]);
                float gg = (acc[2][0] + acc[2][2]) + (acc[2][1] + acc[2][3]);
                float go = (acc[3][0] + acc[3][2]) + (acc[3][1] + acc[3][3]);
                if (act) {
                    float cn = fast_sigmoid(gf) * cst + fast_sigmoid(gi) * fast_tanh(gg);
                    cst = cn;
                    h1lds[t & 1][ln] = (_Float16)(fast_sigmoid(go) * fast_tanh(cn));
                }
            }
        } else {
            // ======== predict tick: wave1 published h2(t-1); sync, make o ====
            __syncthreads();               // barrier B (fence for h2f32)
            float part = act ? h2f32[(t + 1) & 1][ln] * wlin_l : 0.0f;
            #pragma unroll
            for (int off = 32; off > 0; off >>= 1)
                part += __shfl_down(part, off);
            float o = __shfl(part, 0) + blin;
            if (tid == 0) out[(size_t)b * S + (t - 1)] = o;
            if (isProd && t < S) {         // wave0: G1(t) with xin = o(t-1)
                float acc[4][4];
                #pragma unroll
                for (int q = 0; q < 4; ++q) {
                    acc[q][0] = bv[q] + o * wih[q];
                    acc[q][1] = 0.0f; acc[q][2] = 0.0f; acc[q][3] = 0.0f;
                }
                const int s1 = (t + 1) & 1;
                #pragma unroll
                for (int L = 0; L < 6; ++L) {
                    float4 f = *(const float4*)&h1lds[s1][8 * L];
                    #pragma unroll
                    for (int j = 0; j < 4; ++j) {
                        const float hj = (&f.x)[j];
                        #pragma unroll
                        for (int q = 0; q < 4; ++q)
                            acc[q][j] = FDOT2(wgtA[q][4*L + j], BC(hj), acc[q][j]);
                    }
                }
                {
                    const float h24 = *(const float*)&h1lds[s1][48];
                    #pragma unroll
                    for (int q = 0; q < 4; ++q)
                        acc[q][0] = FDOT2(wgtA[q][24], BC(h24), acc[q][0]);
                }
                float gi = (acc[0][0] + acc[0][2]) + (acc[0][1] + acc[0][3]);
                float gf = (acc[1][0] + acc[1][2]) + (acc[1][1] + acc[1][3]);
                float gg = (acc[2][0] + acc[2][2]) + (acc[2][1] + acc[2][3]);
                float go = (acc[3][0] + acc[3][2]) + (acc[3][1] + acc[3][3]);
                if (act) {
                    float cn = fast_sigmoid(gf) * cst + fast_sigmoid(gi) * fast_tanh(gg);
                    cst = cn;
                    h1lds[t & 1][ln] = (_Float16)(fast_sigmoid(go) * fast_tanh(cn));
                }
            }
        }
    }
}

extern "C" void kernel_launch(void* const* d_in, const int* in_sizes, int n_in,
                              void* d_out, int out_size, void* d_ws, size_t ws_size,
                              hipStream_t stream) {
    const float* x      = (const float*)d_in[0];
    const float* W_ih1  = (const float*)d_in[1];
    const float* W_hh1  = (const float*)d_in[2];
    const float* b_ih1  = (const float*)d_in[3];
    const float* b_hh1  = (const float*)d_in[4];
    const float* W_ih2  = (const float*)d_in[5];
    const float* W_hh2  = (const float*)d_in[6];
    const float* b_ih2  = (const float*)d_in[7];
    const float* b_hh2  = (const float*)d_in[8];
    const float* W_lin  = (const float*)d_in[9];
    const float* b_lin  = (const float*)d_in[10];
    const int*   pred   = (const int*)d_in[11];
    float* out = (float*)d_out;

    const int B = 512;                 // fixed by setup_inputs
    const int T = in_sizes[0] / B;     // 1024

    dim3 grid(B), block(128);
    hipLaunchKernelGGL(sine_lstm_kernel, grid, block, 0, stream,
                       x, W_ih1, W_hh1, b_ih1, b_hh1,
                       W_ih2, W_hh2, b_ih2, b_hh2,
                       W_lin, b_lin, pred, out, T);
}